// Round 11
// baseline (266.449 us; speedup 1.0000x reference)
//
#include <hip/hip_runtime.h>

#define LOG2E 1.4426950408889634f
#define NB 4
#define NL 256
#define ND 256
#define NH 256

typedef __attribute__((ext_vector_type(8))) short s16x8;
typedef __attribute__((ext_vector_type(4))) short s16x4;
typedef __attribute__((ext_vector_type(4))) float f32x4;

static __device__ __forceinline__ float b2f(unsigned short u) {
  return __builtin_bit_cast(float, (unsigned int)u << 16);
}
static __device__ __forceinline__ unsigned short f2b(float f) {
  unsigned int x = __builtin_bit_cast(unsigned int, f);
  return (unsigned short)((x + 0x7fffu + ((x >> 16) & 1u)) >> 16);
}
static __device__ __forceinline__ float ftanh(float x) {
  float e = __builtin_amdgcn_exp2f(x * 2.8853900817779268f);
  return 1.0f - 2.0f * __builtin_amdgcn_rcpf(e + 1.0f);
}

// ws layout (4.5 MB, R9-proven size):
//   X    fp32 [0,    1M)  : Hq@Wb
//   C1   bf16 [1M, 1.5M)  : Hq@Wc1
//   M1   bf16 [1.5M, 2M)  : Hq@Wm
//   C2b  bf16 [2M, 2.5M)  : Hp@Wc2
//   M2b  bf16 [2.5M, 3M)  : Hp@Wm
//   Hqb  bf16 [3M, 3.5M)  : bf16(Hq)
//   WdTb bf16 [3.5M, 4M)  : bf16(Wd^T)  [h][k]
//   SDb  bf16 [4M, 4.5M)  : branch-d raw scores

__global__ void __launch_bounds__(256) prep(
    const float* __restrict__ Hq, const float* __restrict__ Hp,
    const float* __restrict__ Wc1, const float* __restrict__ Wc2,
    const float* __restrict__ Wb, const float* __restrict__ Wm,
    const float* __restrict__ Wd, float* __restrict__ ws)
{
  const int which = blockIdx.y;  // 0=C1 1=M1 2=X 3=C2b 4=M2b 5=Hqb 6=WdTb
  const int tid = threadIdx.x;
  if (which == 6) { // LDS-tile transpose Wd[k][h] -> WdTb[h][k] bf16
    if (blockIdx.x >= 16) return;
    const int k0 = (blockIdx.x >> 2) * 64, h0 = (blockIdx.x & 3) * 64;
    __shared__ unsigned short tile[64][65];
    unsigned short* WdTb = (unsigned short*)((char*)ws + 3670016);
    #pragma unroll
    for (int i = 0; i < 16; ++i) {
      const int idx = i * 256 + tid;
      const int kk = idx >> 6, hh = idx & 63;
      tile[kk][hh] = f2b(Wd[(k0 + kk) * NH + h0 + hh]);
    }
    __syncthreads();
    #pragma unroll
    for (int i = 0; i < 16; ++i) {
      const int idx = i * 256 + tid;
      const int hh = idx >> 6, kk = idx & 63;
      WdTb[(h0 + hh) * ND + k0 + kk] = tile[kk][hh];
    }
    return;
  }
  const int m0 = blockIdx.x * 8;
  if (which == 5) {
    unsigned short* Hqb = (unsigned short*)((char*)ws + 3145728);
    #pragma unroll
    for (int j = 0; j < 8; ++j)
      Hqb[(m0 + j) * ND + tid] = f2b(Hq[(m0 + j) * ND + tid]);
    return;
  }
  __shared__ __align__(16) float a_s[8][256];
  const float* A = (which >= 3) ? Hp : Hq;
  const float* W = (which == 0) ? Wc1 : (which == 1) ? Wm :
                   (which == 2) ? Wb  : (which == 3) ? Wc2 : Wm;
  #pragma unroll
  for (int j = 0; j < 8; ++j)
    a_s[j][tid] = A[(m0 + j) * ND + tid];
  __syncthreads();
  float acc[8] = {0.f, 0.f, 0.f, 0.f, 0.f, 0.f, 0.f, 0.f};
  for (int k = 0; k < 256; k += 4) {
    f32x4 av[8];
    #pragma unroll
    for (int j = 0; j < 8; ++j) av[j] = *(const f32x4*)&a_s[j][k];
    #pragma unroll
    for (int kk = 0; kk < 4; ++kk) {
      const float w = W[(k + kk) * NH + tid];
      #pragma unroll
      for (int j = 0; j < 8; ++j) acc[j] += av[j][kk] * w;
    }
  }
  if (which == 2) {
    #pragma unroll
    for (int j = 0; j < 8; ++j) ws[(m0 + j) * NH + tid] = acc[j];
  } else {
    const int base = (which < 2) ? (1048576 + which * 524288)
                                 : (2097152 + (which - 3) * 524288);
    unsigned short* O = (unsigned short*)((char*)ws + base);
    #pragma unroll
    for (int j = 0; j < 8; ++j) O[(m0 + j) * NH + tid] = f2b(acc[j]);
  }
}

// ---- branch d: per (b,p) MFMA GEMM + tanh reduce -> SDb (half-K LDS staging)
__global__ void __launch_bounds__(256) dkernel(
    const float* __restrict__ Hp, const float* __restrict__ vd,
    float* __restrict__ ws)
{
  const int p = blockIdx.x, b = blockIdx.y;
  const int tid = threadIdx.x;
  const int wave = tid >> 6, lane = tid & 63;
  const int quad = lane >> 4, c16 = lane & 15;

  __shared__ __align__(16) short Bs[64 * 136];  // [h][k-half], 17.4 KB
  __shared__ __align__(16) float hp_s[256];
  __shared__ __align__(16) float vd_s[256];

  const unsigned short* Hqb  = (const unsigned short*)((const char*)ws + 3145728);
  const unsigned short* WdTb = (const unsigned short*)((const char*)ws + 3670016);
  unsigned short* SDb = (unsigned short*)((char*)ws + 4194304);

  hp_s[tid] = Hp[(b * NL + p) * ND + tid];
  vd_s[tid] = vd[tid];
  __syncthreads();

  const int wq0 = wave * 64;
  const unsigned short* Aq = Hqb + (b * NL + wq0) * ND;
  float sd_reg[4][4];
  #pragma unroll
  for (int mt = 0; mt < 4; ++mt)
    #pragma unroll
    for (int r = 0; r < 4; ++r) sd_reg[mt][r] = 0.f;

  const int sh = tid & 63;     // staging h
  const int skq = tid >> 6;    // staging k-chunk (32 wide)

  for (int ht = 0; ht < 4; ++ht) {
    const int h0 = ht * 64;
    f32x4 acc[4][4];
    #pragma unroll
    for (int mt = 0; mt < 4; ++mt)
      #pragma unroll
      for (int nt = 0; nt < 4; ++nt) acc[mt][nt] = f32x4{0.f, 0.f, 0.f, 0.f};

    for (int kh = 0; kh < 2; ++kh) {
      const int kbase = kh * 128;
      __syncthreads();
      { // stage Bs[h][k'] = bf16(WdTb[h0+h][kbase+k'] * hp[kbase+k'])
        const unsigned short* src = WdTb + (h0 + sh) * ND + kbase + skq * 32;
        short* dst = Bs + sh * 136 + skq * 32;
        #pragma unroll
        for (int i = 0; i < 4; ++i) {
          s16x8 w8 = *(const s16x8*)(src + i * 8);
          s16x8 bv;
          #pragma unroll
          for (int j = 0; j < 8; ++j)
            bv[j] = (short)f2b(b2f((unsigned short)w8[j]) *
                               hp_s[kbase + skq * 32 + i * 8 + j]);
          *(s16x8*)(dst + i * 8) = bv;
        }
      }
      __syncthreads();

      #pragma unroll
      for (int kt = 0; kt < 4; ++kt) {
        const int k0 = kt * 32;
        s16x8 a8[4];
        #pragma unroll
        for (int mt = 0; mt < 4; ++mt)
          a8[mt] = *(const s16x8*)(Aq + (mt * 16 + c16) * ND + kbase + k0 + quad * 8);
        #pragma unroll
        for (int nt = 0; nt < 4; ++nt) {
          s16x8 b8 = *(const s16x8*)(Bs + (nt * 16 + c16) * 136 + k0 + quad * 8);
          #pragma unroll
          for (int mt = 0; mt < 4; ++mt)
            acc[mt][nt] = __builtin_amdgcn_mfma_f32_16x16x32_bf16(
                a8[mt], b8, acc[mt][nt], 0, 0, 0);
        }
      }
    }

    // sd[q] += sum_h vd[h]*tanh(Z[q,h]); C/D: col=lane&15, row=quad*4+r
    #pragma unroll
    for (int mt = 0; mt < 4; ++mt) {
      float part[4] = {0.f, 0.f, 0.f, 0.f};
      #pragma unroll
      for (int nt = 0; nt < 4; ++nt) {
        const float vdh = vd_s[h0 + nt * 16 + c16];
        #pragma unroll
        for (int r = 0; r < 4; ++r)
          part[r] += vdh * ftanh(acc[mt][nt][r]);
      }
      #pragma unroll
      for (int r = 0; r < 4; ++r) {
        float v = part[r];
        #pragma unroll
        for (int m = 1; m < 16; m <<= 1) v += __shfl_xor(v, m, 64);
        sd_reg[mt][r] += v;
      }
    }
  }
  if (c16 == 0) {
    unsigned short* SD = SDb + (b * NL + p) * NL;
    #pragma unroll
    for (int mt = 0; mt < 4; ++mt)
      #pragma unroll
      for (int r = 0; r < 4; ++r)
        SD[wq0 + mt * 16 + quad * 4 + r] = f2b(sd_reg[mt][r]);
  }
}

// ---- scores c/b/m + softmax(all 4) + attend(all 4) (R9-style integrated)
__global__ void __launch_bounds__(256) fused2(
    const float* __restrict__ Hp, const float* __restrict__ Hq,
    const float* __restrict__ vc, const float* __restrict__ vm,
    const float* __restrict__ ws, float* __restrict__ out)
{
  const int p = blockIdx.x, b = blockIdx.y;
  const int tid = threadIdx.x;
  const int wave = tid >> 6, lane = tid & 63;
  const int c16 = lane & 15;

  __shared__ __align__(16) float sc4[4 * 256];   // rows: 0=c 1=b 2=d 3=m
  __shared__ __align__(16) float red[4][4][256]; // [wave][branch][d]
  __shared__ __align__(16) float hp_s[256];
  __shared__ __align__(16) float c2_s[256];
  __shared__ __align__(16) float m2_s[256];
  __shared__ __align__(16) float vc_s[256];
  __shared__ __align__(16) float vm_s[256];
  __shared__ __align__(16) float invsum[4];

  const float* X = ws;
  const unsigned short* C1  = (const unsigned short*)((const char*)ws + 1048576);
  const unsigned short* M1  = (const unsigned short*)((const char*)ws + 1572864);
  const unsigned short* C2b = (const unsigned short*)((const char*)ws + 2097152);
  const unsigned short* M2b = (const unsigned short*)((const char*)ws + 2621440);
  const unsigned short* SDb = (const unsigned short*)((const char*)ws + 4194304);

  {
    const int r = (b * NL + p) * ND + tid;
    hp_s[tid] = Hp[r];
    c2_s[tid] = b2f(C2b[r]);
    m2_s[tid] = b2f(M2b[r]);
    vc_s[tid] = vc[tid];
    vm_s[tid] = vm[tid];
    sc4[512 + tid] = b2f(SDb[(b * NL + p) * NL + tid]);
  }
  __syncthreads();

  { // scores c, b, m: lane c16 covers 8-wide h chunks at c16*8 + {0,128}
    const int qsub = lane >> 4;
    const int hb = c16 * 8;
    #pragma unroll 2
    for (int qg = 0; qg < 16; ++qg) {
      const int q = wave * 64 + qg * 4 + qsub;
      const unsigned short* c1r = C1 + (b * NL + q) * NH;
      const unsigned short* m1r = M1 + (b * NL + q) * NH;
      const float* xr = X + (b * NL + q) * ND;
      float pc = 0.f, pm = 0.f, pb = 0.f;
      #pragma unroll
      for (int hi = 0; hi < 2; ++hi) {
        const int h = hb + hi * 128;
        s16x8 c1v = *(const s16x8*)(c1r + h);
        s16x8 m1v = *(const s16x8*)(m1r + h);
        f32x4 xv0 = *(const f32x4*)(xr + h);
        f32x4 xv1 = *(const f32x4*)(xr + h + 4);
        f32x4 c20 = *(const f32x4*)(c2_s + h);
        f32x4 c21 = *(const f32x4*)(c2_s + h + 4);
        f32x4 m20 = *(const f32x4*)(m2_s + h);
        f32x4 m21 = *(const f32x4*)(m2_s + h + 4);
        f32x4 vc0 = *(const f32x4*)(vc_s + h);
        f32x4 vc1 = *(const f32x4*)(vc_s + h + 4);
        f32x4 vm0 = *(const f32x4*)(vm_s + h);
        f32x4 vm1 = *(const f32x4*)(vm_s + h + 4);
        f32x4 hp0 = *(const f32x4*)(hp_s + h);
        f32x4 hp1 = *(const f32x4*)(hp_s + h + 4);
        #pragma unroll
        for (int i = 0; i < 4; ++i) {
          pc += vc0[i] * ftanh(b2f((unsigned short)c1v[i]) + c20[i]);
          pm += vm0[i] * ftanh(b2f((unsigned short)m1v[i]) - m20[i]);
          pb += hp0[i] * xv0[i];
        }
        #pragma unroll
        for (int i = 0; i < 4; ++i) {
          pc += vc1[i] * ftanh(b2f((unsigned short)c1v[4 + i]) + c21[i]);
          pm += vm1[i] * ftanh(b2f((unsigned short)m1v[4 + i]) - m21[i]);
          pb += hp1[i] * xv1[i];
        }
      }
      #pragma unroll
      for (int m = 1; m < 16; m <<= 1) {
        pc += __shfl_xor(pc, m, 64);
        pm += __shfl_xor(pm, m, 64);
        pb += __shfl_xor(pb, m, 64);
      }
      if (c16 == 0) {
        sc4[q]       = pc;
        sc4[256 + q] = pb;
        sc4[768 + q] = pm;
      }
    }
  }
  __syncthreads();

  { // softmax; wave w owns branch w
    float s0 = sc4[wave * 256 + lane];
    float s1 = sc4[wave * 256 + lane + 64];
    float s2 = sc4[wave * 256 + lane + 128];
    float s3 = sc4[wave * 256 + lane + 192];
    float mx = fmaxf(fmaxf(s0, s1), fmaxf(s2, s3));
    #pragma unroll
    for (int m = 1; m < 64; m <<= 1) mx = fmaxf(mx, __shfl_xor(mx, m, 64));
    float e0 = __builtin_amdgcn_exp2f((s0 - mx) * LOG2E);
    float e1 = __builtin_amdgcn_exp2f((s1 - mx) * LOG2E);
    float e2 = __builtin_amdgcn_exp2f((s2 - mx) * LOG2E);
    float e3 = __builtin_amdgcn_exp2f((s3 - mx) * LOG2E);
    float sm = e0 + e1 + e2 + e3;
    #pragma unroll
    for (int m = 1; m < 64; m <<= 1) sm += __shfl_xor(sm, m, 64);
    sc4[wave * 256 + lane]       = e0;
    sc4[wave * 256 + lane + 64]  = e1;
    sc4[wave * 256 + lane + 128] = e2;
    sc4[wave * 256 + lane + 192] = e3;
    if (lane == 0) invsum[wave] = __builtin_amdgcn_rcpf(sm);
  }
  __syncthreads();

  { // attend: wave w covers q in [64w,64w+64) for ALL branches
    const int q0 = wave * 64;
    f32x4 pa0 = {0.f,0.f,0.f,0.f}, pa1 = {0.f,0.f,0.f,0.f};
    f32x4 pa2 = {0.f,0.f,0.f,0.f}, pa3 = {0.f,0.f,0.f,0.f};
    for (int qi = 0; qi < 64; ++qi) {
      const int q = q0 + qi;
      const float ac = sc4[q];
      const float ab = sc4[256 + q];
      const float ad = sc4[512 + q];
      const float am = sc4[768 + q];
      f32x4 hv = *(const f32x4*)(Hq + (b * NL + q) * ND + lane * 4);
      pa0 += ac * hv; pa1 += ab * hv; pa2 += ad * hv; pa3 += am * hv;
    }
    *(f32x4*)(&red[wave][0][lane * 4]) = pa0;
    *(f32x4*)(&red[wave][1][lane * 4]) = pa1;
    *(f32x4*)(&red[wave][2][lane * 4]) = pa2;
    *(f32x4*)(&red[wave][3][lane * 4]) = pa3;
  }
  __syncthreads();

  #pragma unroll
  for (int br = 0; br < 4; ++br) {
    float s = red[0][br][tid] + red[1][br][tid] + red[2][br][tid] + red[3][br][tid];
    out[((br * NB + b) * NL + p) * ND + tid] = s * invsum[br];
  }
}

extern "C" void kernel_launch(void* const* d_in, const int* in_sizes, int n_in,
                              void* d_out, int out_size, void* d_ws, size_t ws_size,
                              hipStream_t stream) {
  const float* Hp  = (const float*)d_in[0];
  const float* Hq  = (const float*)d_in[1];
  const float* Wc1 = (const float*)d_in[2];
  const float* Wc2 = (const float*)d_in[3];
  const float* vc  = (const float*)d_in[4];
  const float* Wb  = (const float*)d_in[5];
  const float* Wd  = (const float*)d_in[6];
  const float* vd  = (const float*)d_in[7];
  const float* Wm  = (const float*)d_in[8];
  const float* vm  = (const float*)d_in[9];
  float* ws = (float*)d_ws;
  float* out = (float*)d_out;

  hipLaunchKernelGGL(prep, dim3(128, 7), dim3(256), 0, stream,
                     Hq, Hp, Wc1, Wc2, Wb, Wm, Wd, ws);
  hipLaunchKernelGGL(dkernel, dim3(256, 4), dim3(256), 0, stream,
                     Hp, vd, ws);
  hipLaunchKernelGGL(fused2, dim3(256, 4), dim3(256), 0, stream,
                     Hp, Hq, vc, vm, ws, out);
}

// Round 12
// 235.147 us; speedup vs baseline: 1.1331x; 1.1331x over previous
//
#include <hip/hip_runtime.h>

#define LOG2E 1.4426950408889634f
#define NB 4
#define NL 256
#define ND 256
#define NH 256

typedef __attribute__((ext_vector_type(8))) short s16x8;
typedef __attribute__((ext_vector_type(4))) short s16x4;
typedef __attribute__((ext_vector_type(4))) float f32x4;

static __device__ __forceinline__ float b2f(unsigned short u) {
  return __builtin_bit_cast(float, (unsigned int)u << 16);
}
static __device__ __forceinline__ unsigned short f2b(float f) {
  unsigned int x = __builtin_bit_cast(unsigned int, f);
  return (unsigned short)((x + 0x7fffu + ((x >> 16) & 1u)) >> 16);
}
static __device__ __forceinline__ float ftanh(float x) {
  float e = __builtin_amdgcn_exp2f(x * 2.8853900817779268f);
  return 1.0f - 2.0f * __builtin_amdgcn_rcpf(e + 1.0f);
}

// ws layout (4 MB):
//   X    fp32 [0,    1M)  : Hq@Wb
//   C1   bf16 [1M, 1.5M)  : Hq@Wc1
//   M1   bf16 [1.5M, 2M)  : Hq@Wm
//   C2b  bf16 [2M, 2.5M)  : Hp@Wc2
//   M2b  bf16 [2.5M, 3M)  : Hp@Wm
//   Hqb  bf16 [3M, 3.5M)  : bf16(Hq)
//   WdTb bf16 [3.5M, 4M)  : bf16(Wd^T) [h][k]
// Branch-d partial scores (SDP) live in d_out (4 MB) between dkernel and
// fused2; fused2 block (p,b) reads exactly the bytes it later overwrites.

__global__ void __launch_bounds__(256) prep(
    const float* __restrict__ Hq, const float* __restrict__ Hp,
    const float* __restrict__ Wc1, const float* __restrict__ Wc2,
    const float* __restrict__ Wb, const float* __restrict__ Wm,
    const float* __restrict__ Wd, float* __restrict__ ws)
{
  const int which = blockIdx.y;  // 0=C1 1=M1 2=X 3=C2b 4=M2b 5=Hqb 6=WdTb
  const int tid = threadIdx.x;
  if (which == 6) { // LDS-tile transpose Wd[k][h] -> WdTb[h][k] bf16
    if (blockIdx.x >= 16) return;
    const int k0 = (blockIdx.x >> 2) * 64, h0 = (blockIdx.x & 3) * 64;
    __shared__ unsigned short tile[64][65];
    unsigned short* WdTb = (unsigned short*)((char*)ws + 3670016);
    #pragma unroll
    for (int i = 0; i < 16; ++i) {
      const int idx = i * 256 + tid;
      const int kk = idx >> 6, hh = idx & 63;
      tile[kk][hh] = f2b(Wd[(k0 + kk) * NH + h0 + hh]);
    }
    __syncthreads();
    #pragma unroll
    for (int i = 0; i < 16; ++i) {
      const int idx = i * 256 + tid;
      const int hh = idx >> 6, kk = idx & 63;
      WdTb[(h0 + hh) * ND + k0 + kk] = tile[kk][hh];
    }
    return;
  }
  const int m0 = blockIdx.x * 8;
  if (which == 5) {
    unsigned short* Hqb = (unsigned short*)((char*)ws + 3145728);
    #pragma unroll
    for (int j = 0; j < 8; ++j)
      Hqb[(m0 + j) * ND + tid] = f2b(Hq[(m0 + j) * ND + tid]);
    return;
  }
  __shared__ __align__(16) float a_s[8][256];
  const float* A = (which >= 3) ? Hp : Hq;
  const float* W = (which == 0) ? Wc1 : (which == 1) ? Wm :
                   (which == 2) ? Wb  : (which == 3) ? Wc2 : Wm;
  #pragma unroll
  for (int j = 0; j < 8; ++j)
    a_s[j][tid] = A[(m0 + j) * ND + tid];
  __syncthreads();
  float acc[8] = {0.f, 0.f, 0.f, 0.f, 0.f, 0.f, 0.f, 0.f};
  for (int k = 0; k < 256; k += 4) {
    f32x4 av[8];
    #pragma unroll
    for (int j = 0; j < 8; ++j) av[j] = *(const f32x4*)&a_s[j][k];
    #pragma unroll
    for (int kk = 0; kk < 4; ++kk) {
      const float w = W[(k + kk) * NH + tid];
      #pragma unroll
      for (int j = 0; j < 8; ++j) acc[j] += av[j][kk] * w;
    }
  }
  if (which == 2) {
    #pragma unroll
    for (int j = 0; j < 8; ++j) ws[(m0 + j) * NH + tid] = acc[j];
  } else {
    const int base = (which < 2) ? (1048576 + which * 524288)
                                 : (2097152 + (which - 3) * 524288);
    unsigned short* O = (unsigned short*)((char*)ws + base);
    #pragma unroll
    for (int j = 0; j < 8; ++j) O[(m0 + j) * NH + tid] = f2b(acc[j]);
  }
}

// ---- branch d: block = (p, ht); 2 barriers; partials -> out (SDP)
__global__ void __launch_bounds__(256) dkernel(
    const float* __restrict__ Hp, const float* __restrict__ vd,
    const float* __restrict__ ws, float* __restrict__ out)
{
  const int p = blockIdx.x >> 2, ht = blockIdx.x & 3, b = blockIdx.y;
  const int h0 = ht * 64;
  const int tid = threadIdx.x;
  const int wave = tid >> 6, lane = tid & 63;
  const int quad = lane >> 4, c16 = lane & 15;

  __shared__ __align__(16) short Bs[64 * 264];  // [h][k] full-K, 33.8 KB
  __shared__ __align__(16) float hp_s[256];
  __shared__ __align__(16) float vd_s[256];

  const unsigned short* Hqb  = (const unsigned short*)((const char*)ws + 3145728);
  const unsigned short* WdTb = (const unsigned short*)((const char*)ws + 3670016);

  hp_s[tid] = Hp[(b * NL + p) * ND + tid];
  vd_s[tid] = vd[tid];
  __syncthreads();

  { // stage Bs[h][k] = bf16(WdTb[h0+h][k] * hp[k]); thread: h=tid&63, k-quarter
    const int sh = tid & 63, skq = tid >> 6;
    const unsigned short* src = WdTb + (h0 + sh) * ND + skq * 64;
    short* dst = Bs + sh * 264 + skq * 64;
    #pragma unroll
    for (int i = 0; i < 8; ++i) {
      s16x8 w8 = *(const s16x8*)(src + i * 8);
      s16x8 bv;
      #pragma unroll
      for (int j = 0; j < 8; ++j)
        bv[j] = (short)f2b(b2f((unsigned short)w8[j]) * hp_s[skq * 64 + i * 8 + j]);
      *(s16x8*)(dst + i * 8) = bv;
    }
  }
  __syncthreads();

  const int wq0 = wave * 64;
  const unsigned short* Aq = Hqb + (b * NL + wq0) * ND;

  f32x4 acc[4][4];
  #pragma unroll
  for (int mt = 0; mt < 4; ++mt)
    #pragma unroll
    for (int nt = 0; nt < 4; ++nt) acc[mt][nt] = f32x4{0.f, 0.f, 0.f, 0.f};

  #pragma unroll 2
  for (int kt = 0; kt < 8; ++kt) {
    const int k0 = kt * 32;
    s16x8 a8[4];
    #pragma unroll
    for (int mt = 0; mt < 4; ++mt)
      a8[mt] = *(const s16x8*)(Aq + (mt * 16 + c16) * ND + k0 + quad * 8);
    #pragma unroll
    for (int nt = 0; nt < 4; ++nt) {
      s16x8 b8 = *(const s16x8*)(Bs + (nt * 16 + c16) * 264 + k0 + quad * 8);
      #pragma unroll
      for (int mt = 0; mt < 4; ++mt)
        acc[mt][nt] = __builtin_amdgcn_mfma_f32_16x16x32_bf16(
            a8[mt], b8, acc[mt][nt], 0, 0, 0);
    }
  }

  // sd_partial[q] = sum_{h in this ht} vd[h]*tanh(Z[q,h])
  // C/D layout: col=lane&15 (h), row=quad*4+r (q)
  #pragma unroll
  for (int mt = 0; mt < 4; ++mt) {
    float part[4] = {0.f, 0.f, 0.f, 0.f};
    #pragma unroll
    for (int nt = 0; nt < 4; ++nt) {
      const float vdh = vd_s[h0 + nt * 16 + c16];
      #pragma unroll
      for (int r = 0; r < 4; ++r)
        part[r] += vdh * ftanh(acc[mt][nt][r]);
    }
    #pragma unroll
    for (int r = 0; r < 4; ++r) {
      float v = part[r];
      #pragma unroll
      for (int m = 1; m < 16; m <<= 1) v += __shfl_xor(v, m, 64);
      if (c16 == 0)
        out[((ht * NB + b) * NL + p) * ND + wq0 + mt * 16 + quad * 4 + r] = v;
    }
  }
}

// ---- scores c/b/m + softmax + attend; 512 threads (8 waves)
__global__ void __launch_bounds__(512) fused2(
    const float* __restrict__ Hp, const float* __restrict__ Hq,
    const float* __restrict__ vc, const float* __restrict__ vm,
    const float* __restrict__ ws, float* __restrict__ out)
{
  const int p = blockIdx.x, b = blockIdx.y;
  const int tid = threadIdx.x;
  const int wave = tid >> 6, lane = tid & 63;
  const int c16 = lane & 15;

  __shared__ __align__(16) float sc4[4 * 256];    // 0=c 1=b 2=d 3=m
  __shared__ __align__(16) float red[16][256];    // [slot][d]
  __shared__ __align__(16) float hp_s[256];
  __shared__ __align__(16) float c2_s[256];
  __shared__ __align__(16) float m2_s[256];
  __shared__ __align__(16) float vc_s[256];
  __shared__ __align__(16) float vm_s[256];
  __shared__ __align__(16) float invsum[4];

  const float* X = ws;
  const unsigned short* C1  = (const unsigned short*)((const char*)ws + 1048576);
  const unsigned short* M1  = (const unsigned short*)((const char*)ws + 1572864);
  const unsigned short* C2b = (const unsigned short*)((const char*)ws + 2097152);
  const unsigned short* M2b = (const unsigned short*)((const char*)ws + 2621440);

  if (tid < 256) {
    const int r = (b * NL + p) * ND + tid;
    hp_s[tid] = Hp[r];
    c2_s[tid] = b2f(C2b[r]);
    m2_s[tid] = b2f(M2b[r]);
    vc_s[tid] = vc[tid];
    vm_s[tid] = vm[tid];
  } else {
    const int q = tid - 256;
    const int base = (b * NL + p) * ND + q;
    // sum the 4 ht partials of branch-d scores (SDP written by dkernel)
    sc4[512 + q] = out[base] + out[(1 * NB * NL * ND) + base] +
                   out[(2 * NB * NL * ND) + base] + out[(3 * NB * NL * ND) + base];
  }
  __syncthreads();

  { // scores c, b, m: wave owns q in [32w, 32w+32)
    const int qsub = lane >> 4;
    const int hb = c16 * 8;
    for (int qg = 0; qg < 8; ++qg) {
      const int q = wave * 32 + qg * 4 + qsub;
      const unsigned short* c1r = C1 + (b * NL + q) * NH;
      const unsigned short* m1r = M1 + (b * NL + q) * NH;
      const float* xr = X + (b * NL + q) * ND;
      float pc = 0.f, pm = 0.f, pb = 0.f;
      #pragma unroll
      for (int hi = 0; hi < 2; ++hi) {
        const int h = hb + hi * 128;
        s16x8 c1v = *(const s16x8*)(c1r + h);
        s16x8 m1v = *(const s16x8*)(m1r + h);
        f32x4 xv0 = *(const f32x4*)(xr + h);
        f32x4 xv1 = *(const f32x4*)(xr + h + 4);
        f32x4 c20 = *(const f32x4*)(c2_s + h);
        f32x4 c21 = *(const f32x4*)(c2_s + h + 4);
        f32x4 m20 = *(const f32x4*)(m2_s + h);
        f32x4 m21 = *(const f32x4*)(m2_s + h + 4);
        f32x4 vc0 = *(const f32x4*)(vc_s + h);
        f32x4 vc1 = *(const f32x4*)(vc_s + h + 4);
        f32x4 vm0 = *(const f32x4*)(vm_s + h);
        f32x4 vm1 = *(const f32x4*)(vm_s + h + 4);
        f32x4 hp0 = *(const f32x4*)(hp_s + h);
        f32x4 hp1 = *(const f32x4*)(hp_s + h + 4);
        #pragma unroll
        for (int i = 0; i < 4; ++i) {
          pc += vc0[i] * ftanh(b2f((unsigned short)c1v[i]) + c20[i]);
          pm += vm0[i] * ftanh(b2f((unsigned short)m1v[i]) - m20[i]);
          pb += hp0[i] * xv0[i];
        }
        #pragma unroll
        for (int i = 0; i < 4; ++i) {
          pc += vc1[i] * ftanh(b2f((unsigned short)c1v[4 + i]) + c21[i]);
          pm += vm1[i] * ftanh(b2f((unsigned short)m1v[4 + i]) - m21[i]);
          pb += hp1[i] * xv1[i];
        }
      }
      #pragma unroll
      for (int m = 1; m < 16; m <<= 1) {
        pc += __shfl_xor(pc, m, 64);
        pm += __shfl_xor(pm, m, 64);
        pb += __shfl_xor(pb, m, 64);
      }
      if (c16 == 0) {
        sc4[q]       = pc;
        sc4[256 + q] = pb;
        sc4[768 + q] = pm;
      }
    }
  }
  __syncthreads();

  if (wave < 4) { // softmax; wave w owns branch w
    float s0 = sc4[wave * 256 + lane];
    float s1 = sc4[wave * 256 + lane + 64];
    float s2 = sc4[wave * 256 + lane + 128];
    float s3 = sc4[wave * 256 + lane + 192];
    float mx = fmaxf(fmaxf(s0, s1), fmaxf(s2, s3));
    #pragma unroll
    for (int m = 1; m < 64; m <<= 1) mx = fmaxf(mx, __shfl_xor(mx, m, 64));
    float e0 = __builtin_amdgcn_exp2f((s0 - mx) * LOG2E);
    float e1 = __builtin_amdgcn_exp2f((s1 - mx) * LOG2E);
    float e2 = __builtin_amdgcn_exp2f((s2 - mx) * LOG2E);
    float e3 = __builtin_amdgcn_exp2f((s3 - mx) * LOG2E);
    float sm = e0 + e1 + e2 + e3;
    #pragma unroll
    for (int m = 1; m < 64; m <<= 1) sm += __shfl_xor(sm, m, 64);
    sc4[wave * 256 + lane]       = e0;
    sc4[wave * 256 + lane + 64]  = e1;
    sc4[wave * 256 + lane + 128] = e2;
    sc4[wave * 256 + lane + 192] = e3;
    if (lane == 0) invsum[wave] = __builtin_amdgcn_rcpf(sm);
  }
  __syncthreads();

  { // attend: waves 0-3 -> branches {0,1}, waves 4-7 -> {2,3}; q-range = (wave&3)
    const int aw = wave & 3;
    const int q0 = aw * 64;
    const int brbase = (wave < 4) ? 0 : 2;
    f32x4 pa0 = {0.f,0.f,0.f,0.f}, pa1 = {0.f,0.f,0.f,0.f};
    for (int qi = 0; qi < 64; ++qi) {
      const int q = q0 + qi;
      const float a0 = sc4[brbase * 256 + q];
      const float a1 = sc4[(brbase + 1) * 256 + q];
      f32x4 hv = *(const f32x4*)(Hq + (b * NL + q) * ND + lane * 4);
      pa0 += a0 * hv;
      pa1 += a1 * hv;
    }
    *(f32x4*)(&red[wave * 2 + 0][lane * 4]) = pa0;
    *(f32x4*)(&red[wave * 2 + 1][lane * 4]) = pa1;
  }
  __syncthreads();

  { // final: each thread handles 2 of the 1024 (br,d) outputs
    #pragma unroll
    for (int e0 = 0; e0 < 2; ++e0) {
      const int e = tid + e0 * 512;
      const int br = e >> 8, d = e & 255;
      const int jslot = (br < 2) ? br : (8 + br - 2);
      float s = 0.f;
      #pragma unroll
      for (int qr = 0; qr < 4; ++qr)
        s += red[jslot + qr * 2][d];
      out[((br * NB + b) * NL + p) * ND + d] = s * invsum[br];
    }
  }
}

extern "C" void kernel_launch(void* const* d_in, const int* in_sizes, int n_in,
                              void* d_out, int out_size, void* d_ws, size_t ws_size,
                              hipStream_t stream) {
  const float* Hp  = (const float*)d_in[0];
  const float* Hq  = (const float*)d_in[1];
  const float* Wc1 = (const float*)d_in[2];
  const float* Wc2 = (const float*)d_in[3];
  const float* vc  = (const float*)d_in[4];
  const float* Wb  = (const float*)d_in[5];
  const float* Wd  = (const float*)d_in[6];
  const float* vd  = (const float*)d_in[7];
  const float* Wm  = (const float*)d_in[8];
  const float* vm  = (const float*)d_in[9];
  float* ws = (float*)d_ws;
  float* out = (float*)d_out;

  hipLaunchKernelGGL(prep, dim3(128, 7), dim3(256), 0, stream,
                     Hq, Hp, Wc1, Wc2, Wb, Wm, Wd, ws);
  hipLaunchKernelGGL(dkernel, dim3(1024, 4), dim3(256), 0, stream,
                     Hp, vd, ws, out);
  hipLaunchKernelGGL(fused2, dim3(256, 4), dim3(512), 0, stream,
                     Hp, Hq, vc, vm, ws, out);
}